// Round 15
// baseline (174.912 us; speedup 1.0000x reference)
//
#include <hip/hip_runtime.h>
#include <cstddef>

// Problem constants
#define Bsz 2
#define Lr  2048
#define Dr  1024
#define Nr  16
#define M_ROWS (Bsz*Lr)          // 4096
#define NPAD   1088              // padded (W_dt | W_B | W_C | zeros), 17 tiles of 64
#define CHUNK  16
#define NCH    (Lr/CHUNK)        // 128

#define GBK 32
#define GNK (Dr/GBK)             // 32 K-iterations (gemm)

typedef __attribute__((ext_vector_type(8))) __bf16 bf16x8;
typedef __attribute__((ext_vector_type(4))) float floatx4;

__device__ __forceinline__ unsigned short f2bf(float f) {
    unsigned u = __float_as_uint(f);
    u += 0x7fffu + ((u >> 16) & 1u);
    return (unsigned short)(u >> 16);
}

__device__ __forceinline__ float bf2f(unsigned short u) {
    return __uint_as_float(((unsigned)u) << 16);
}

__device__ __forceinline__ float softplus_f(float x) {
    // abs threshold is 0.905 -> fast log is fine
    if (x > 0.f) return x + __logf(1.f + __expf(-x));
    return __logf(1.f + __expf(x));
}

__device__ __forceinline__ void gload_lds16(const unsigned short* g, unsigned short* l) {
    __builtin_amdgcn_global_load_lds((const __attribute__((address_space(1))) void*)g,
                                     (__attribute__((address_space(3))) void*)l, 16, 0, 0);
}

// ---------------- K0: fused LayerNorm (blocks 0..4095) + weight-pack (rest) ----------------
__global__ __launch_bounds__(256) void ln_pack_kernel(const float* __restrict__ x,
                                                      const float* __restrict__ gamma,
                                                      const float* __restrict__ beta,
                                                      unsigned short* __restrict__ xnb,
                                                      const float* __restrict__ Wdt,
                                                      const float* __restrict__ WB,
                                                      const float* __restrict__ WC,
                                                      unsigned short* __restrict__ Wcat) {
    if (blockIdx.x >= M_ROWS) {
        int i = (blockIdx.x - M_ROWS) * 256 + threadIdx.x;  // over NPAD*Dr
        int row = i >> 10;
        int col = i & 1023;
        float v;
        if (row < Dr)                 v = Wdt[i];
        else if (row < Dr + Nr)       v = WB[(row - Dr) * Dr + col];
        else if (row < Dr + 2*Nr)     v = WC[(row - Dr - Nr) * Dr + col];
        else                          v = 0.f;
        Wcat[i] = f2bf(v);
        return;
    }
    int row = blockIdx.x;
    int tid = threadIdx.x;
    const float4* xr = (const float4*)(x + (size_t)row * Dr);
    float4 v = xr[tid];
    float s  = v.x + v.y + v.z + v.w;
    float ss = v.x*v.x + v.y*v.y + v.z*v.z + v.w*v.w;
    #pragma unroll
    for (int off = 32; off > 0; off >>= 1) {
        s  += __shfl_down(s, off);
        ss += __shfl_down(ss, off);
    }
    __shared__ float red[8];
    int wid = tid >> 6;
    if ((tid & 63) == 0) { red[wid*2] = s; red[wid*2+1] = ss; }
    __syncthreads();
    if (tid == 0) {
        float S = 0.f, SS = 0.f;
        #pragma unroll
        for (int w = 0; w < 4; w++) { S += red[w*2]; SS += red[w*2+1]; }
        float mu  = S * (1.f/Dr);
        float var = SS * (1.f/Dr) - mu*mu;
        red[0] = mu;
        red[1] = rsqrtf(var + 1e-5f);
    }
    __syncthreads();
    float mu = red[0], rs = red[1];
    float4 g = ((const float4*)gamma)[tid], bt = ((const float4*)beta)[tid];
    float4 o;
    o.x = (v.x - mu) * rs * g.x + bt.x;
    o.y = (v.y - mu) * rs * g.y + bt.y;
    o.z = (v.z - mu) * rs * g.z + bt.z;
    o.w = (v.w - mu) * rs * g.w + bt.w;
    ushort4 ob;
    ob.x = f2bf(o.x); ob.y = f2bf(o.y); ob.z = f2bf(o.z); ob.w = f2bf(o.w);
    ((ushort4*)(xnb + (size_t)row * Dr))[tid] = ob;
}

// ---------------- K2: MFMA GEMM [M_ROWS x NPAD] = xnb @ Wcat^T ----------------
// SINGLE-WAVE blocks (64 thr), 64x64 tile, triple-buffered DMA (R7 structure,
// correctness-proven) + the k-stagger that fixed the 4-wave version in R8 +
// XCD colocation. No __syncthreads exists -> no vmcnt(0) barrier drain at all;
// reads of tile k wait (compiler vmcnt) on DMA issued 2 iters earlier, and
// stagger means the 17 A-sharers / 64 B-sharers touch disjoint L2 lines at any
// instant (R7's 49us was lockstep hot-line camping, same as pre-R8 4-wave).
// XOR swizzle cs = quad ^ ((row>>1)&3) on staging SOURCE addresses: 16 frag
// rows hit 8 distinct bank phases -> 2-way (free) vs R7's 8-way (1.1M cyc).
__global__ __launch_bounds__(64) void gemm_kernel(const unsigned short* __restrict__ xnb,
                                                  const unsigned short* __restrict__ w,
                                                  const float* __restrict__ b_dt,
                                                  unsigned short* __restrict__ dt,
                                                  float* __restrict__ bin,
                                                  float* __restrict__ cin) {
    __shared__ unsigned short As[3][64 * GBK];   // 3 x 4 KB
    __shared__ unsigned short Bs[3][64 * GBK];   // 3 x 4 KB
    int t    = threadIdx.x;
    int lm   = t & 15;
    int quad = t >> 4;
    int bid  = blockIdx.x;             // 1088 blocks = 8 XCD-lanes x 136
    int xcd  = bid & 7;
    int j    = bid >> 3;               // 0..135
    int nt   = j % 17;
    int mt   = (j / 17) * 8 + xcd;     // 0..63; A-tile sharers colocated per XCD
    int Mb = mt * 64;
    int Nb = nt * 64;
    int koff = (mt + nt) & (GNK - 1);

    // staging: issue c (0..3) fills slot s=64c+t -> row 16c+(t>>2), slot-chunk t&3,
    // holding global chunk cg = (t&3) ^ ((t>>3)&3)  [= (s&3) ^ ((row>>1)&3)]
    int cg = (t & 3) ^ ((t >> 3) & 3);
    const unsigned short* Ag = xnb + (size_t)(Mb + (t >> 2)) * Dr + cg * 8;
    const unsigned short* Bg = w   + (size_t)(Nb + (t >> 2)) * Dr + cg * 8;

    // prologue: tiles koff, koff+1 -> bufs 0,1
    #pragma unroll
    for (int s = 0; s < 2; s++) {
        int k0 = ((s + koff) & (GNK - 1)) * GBK;
        #pragma unroll
        for (int c = 0; c < 4; c++) {
            gload_lds16(Ag + (size_t)c * 16 * Dr + k0, &As[s][c * 512] + t * 8);
            gload_lds16(Bg + (size_t)c * 16 * Dr + k0, &Bs[s][c * 512] + t * 8);
        }
    }

    floatx4 acc[4][4] = {};

    #pragma unroll
    for (int kk = 0; kk < GNK; kk++) {
        int cur = kk % 3;
        // fragments of tile kk (compiler vmcnt-waits on DMA issued 2 iters ago)
        bf16x8 a[4], b[4];
        #pragma unroll
        for (int i = 0; i < 4; i++) {
            int ra = i * 16 + lm;
            int csa = quad ^ ((ra >> 1) & 3);
            a[i] = *(const bf16x8*)&As[cur][ra * GBK + csa * 8];
            b[i] = *(const bf16x8*)&Bs[cur][ra * GBK + csa * 8];   // same row index math
        }
        // issue tile kk+2 into the buffer freed by tile kk-1 (wraps harmlessly at end)
        int nb = (kk + 2) % 3;
        int k2 = ((kk + 2 + koff) & (GNK - 1)) * GBK;
        #pragma unroll
        for (int c = 0; c < 4; c++) {
            gload_lds16(Ag + (size_t)c * 16 * Dr + k2, &As[nb][c * 512] + t * 8);
            gload_lds16(Bg + (size_t)c * 16 * Dr + k2, &Bs[nb][c * 512] + t * 8);
        }
        #pragma unroll
        for (int i = 0; i < 4; i++)
            #pragma unroll
            for (int jj = 0; jj < 4; jj++)
                acc[i][jj] = __builtin_amdgcn_mfma_f32_16x16x32_bf16(a[i], b[jj], acc[i][jj], 0, 0, 0);
    }

    // C/D layout: col = lane&15, row = (lane>>4)*4 + reg   [m89/m91]
    #pragma unroll
    for (int i = 0; i < 4; i++) {
        int grow0 = Mb + i * 16 + quad * 4;
        #pragma unroll
        for (int jj = 0; jj < 4; jj++) {
            int gcol = Nb + jj * 16 + lm;
            #pragma unroll
            for (int r = 0; r < 4; r++) {
                float v = acc[i][jj][r];
                int row = grow0 + r;
                if (gcol < Dr) {
                    dt[(size_t)row * Dr + gcol] = f2bf(softplus_f(v + b_dt[gcol]));
                } else if (gcol < Dr + Nr) {
                    bin[(size_t)row * Nr + (gcol - Dr)] = v;
                } else if (gcol < Dr + 2*Nr) {
                    cin[(size_t)row * Nr + (gcol - Dr - Nr)] = v;
                }
            }
        }
    }
}

// ---------------- K3: scan pass 1 (per-chunk local scan; emit S, h_end) ----------------
// CHUNK=16 (measured optimum: 32->16 won -10us, 16->8 lost +7.5us).
__global__ __launch_bounds__(256) void scan1_kernel(const unsigned short* __restrict__ dtb,
                                                    const unsigned short* __restrict__ xnb,
                                                    const float* __restrict__ bin,
                                                    const float* __restrict__ A_log,
                                                    float* __restrict__ Sws,
                                                    unsigned short* __restrict__ hendws) {
    int tid = threadIdx.x;
    int d  = blockIdx.x * 256 + tid;
    int ch = blockIdx.y;
    int b  = blockIdx.z;
    size_t rowbase = (size_t)b * Lr + ch * CHUNK;

    float ac[16];
    #pragma unroll
    for (int i = 0; i < 4; i++) {
        float4 t = ((const float4*)(A_log + (size_t)d * Nr))[i];
        ac[i*4+0] = -__expf(t.x);
        ac[i*4+1] = -__expf(t.y);
        ac[i*4+2] = -__expf(t.z);
        ac[i*4+3] = -__expf(t.w);
    }

    __shared__ float lb[CHUNK * Nr];   // 256 floats: one per thread
    lb[tid] = bin[rowbase * Nr + tid];
    __syncthreads();

    // full register batch: 32 loads in flight
    float dtv[CHUNK], xv[CHUNK];
    {
        const unsigned short* dtp = dtb + rowbase * Dr + d;
        const unsigned short* xp  = xnb + rowbase * Dr + d;
        #pragma unroll
        for (int t = 0; t < CHUNK; t++) {
            dtv[t] = bf2f(dtp[(size_t)t * Dr]);
            xv[t]  = bf2f(xp[(size_t)t * Dr]);
        }
    }

    float h[16];
    #pragma unroll
    for (int n = 0; n < 16; n++) h[n] = 0.f;
    float S = 0.f;

    #pragma unroll
    for (int t = 0; t < CHUNK; t++) {
        float dv = dtv[t];
        S += dv;
        float cm = dv * xv[t];
        const float4* br4 = (const float4*)(lb + t * Nr);
        float4 q0 = br4[0], q1 = br4[1], q2 = br4[2], q3 = br4[3];
        float bb[16] = {q0.x,q0.y,q0.z,q0.w, q1.x,q1.y,q1.z,q1.w,
                        q2.x,q2.y,q2.z,q2.w, q3.x,q3.y,q3.z,q3.w};
        #pragma unroll
        for (int n = 0; n < 16; n++)
            h[n] = __expf(dv * ac[n]) * h[n] + cm * bb[n];
    }

    Sws[(size_t)(b * NCH + ch) * Dr + d] = S;
    size_t obase = ((size_t)(b * NCH + ch) * Nr) * Dr + d;   // [b][ch][n][d]
    #pragma unroll
    for (int n = 0; n < 16; n++)
        hendws[obase + (size_t)n * Dr] = f2bf(h[n]);
}

// ---------------- K4: combine chunk states sequentially (S-recompute, batch-16) ----------------
__global__ __launch_bounds__(256) void combine_kernel(const float* __restrict__ Sws,
                                                      const unsigned short* __restrict__ hendws,
                                                      const float* __restrict__ A_log,
                                                      unsigned short* __restrict__ hinws) {
    int id = blockIdx.x * 256 + threadIdx.x;  // B*N*D = 32768
    int b  = id >> 14;
    int dn = id & 16383;                      // n*Dr + d
    int n  = dn >> 10;
    int d  = dn & 1023;
    float ac = -__expf(A_log[d * Nr + n]);
    size_t sbase = (size_t)b * NCH * Dr + d;
    size_t base  = (size_t)b * NCH * (Nr * Dr) + dn;
    float hin = 0.f;
    for (int cb = 0; cb < NCH; cb += 16) {
        float p16[16], he[16];
        #pragma unroll
        for (int u = 0; u < 16; u++) {
            p16[u] = Sws[sbase + (size_t)(cb + u) * Dr];
            he[u]  = bf2f(hendws[base + (size_t)(cb + u) * (Nr * Dr)]);
        }
        #pragma unroll
        for (int u = 0; u < 16; u++) p16[u] = __expf(p16[u] * ac);
        #pragma unroll
        for (int u = 0; u < 16; u++) {
            size_t idx = base + (size_t)(cb + u) * (Nr * Dr);
            hinws[idx] = f2bf(hin);
            hin = p16[u] * hin + he[u];
        }
    }
}

// ---------------- K5: scan pass 2 (re-scan with h_in; emit y + D*residual) ----------------
__global__ __launch_bounds__(256) void scan2_kernel(const unsigned short* __restrict__ dtb,
                                                    const unsigned short* __restrict__ xnb,
                                                    const float* __restrict__ bin,
                                                    const float* __restrict__ cin,
                                                    const float* __restrict__ A_log,
                                                    const unsigned short* __restrict__ hinws,
                                                    const float* __restrict__ x,
                                                    const float* __restrict__ Dp,
                                                    float* __restrict__ out) {
    int tid = threadIdx.x;
    int d  = blockIdx.x * 256 + tid;
    int ch = blockIdx.y;
    int b  = blockIdx.z;
    size_t rowbase = (size_t)b * Lr + ch * CHUNK;

    float ac[16];
    #pragma unroll
    for (int i = 0; i < 4; i++) {
        float4 t = ((const float4*)(A_log + (size_t)d * Nr))[i];
        ac[i*4+0] = -__expf(t.x);
        ac[i*4+1] = -__expf(t.y);
        ac[i*4+2] = -__expf(t.z);
        ac[i*4+3] = -__expf(t.w);
    }

    __shared__ float lb[CHUNK * Nr];
    __shared__ float lc[CHUNK * Nr];
    lb[tid] = bin[rowbase * Nr + tid];
    lc[tid] = cin[rowbase * Nr + tid];
    __syncthreads();

    // full register batches in flight
    float dtv[CHUNK], xv[CHUNK];
    {
        const unsigned short* dtp = dtb + rowbase * Dr + d;
        const unsigned short* xp  = xnb + rowbase * Dr + d;
        #pragma unroll
        for (int t = 0; t < CHUNK; t++) {
            dtv[t] = bf2f(dtp[(size_t)t * Dr]);
            xv[t]  = bf2f(xp[(size_t)t * Dr]);
        }
    }

    size_t obase = ((size_t)(b * NCH + ch) * Nr) * Dr + d;
    float h[16];
    #pragma unroll
    for (int n = 0; n < 16; n++) h[n] = bf2f(hinws[obase + (size_t)n * Dr]);

    float dp = Dp[d];
    const float* xr = x   + rowbase * Dr + d;
    float* op       = out + rowbase * Dr + d;

    for (int tb = 0; tb < CHUNK; tb += 4) {
        float xr4[4];
        #pragma unroll
        for (int u = 0; u < 4; u++) xr4[u] = xr[(size_t)(tb + u) * Dr];
        #pragma unroll
        for (int u = 0; u < 4; u++) {
            int t = tb + u;
            float dv = dtv[t];
            float cm = dv * xv[t];
            const float4* br4 = (const float4*)(lb + t * Nr);
            const float4* cr4 = (const float4*)(lc + t * Nr);
            float4 q0 = br4[0], q1 = br4[1], q2 = br4[2], q3 = br4[3];
            float4 r0 = cr4[0], r1 = cr4[1], r2 = cr4[2], r3 = cr4[3];
            float bb[16] = {q0.x,q0.y,q0.z,q0.w, q1.x,q1.y,q1.z,q1.w,
                            q2.x,q2.y,q2.z,q2.w, q3.x,q3.y,q3.z,q3.w};
            float cc[16] = {r0.x,r0.y,r0.z,r0.w, r1.x,r1.y,r1.z,r1.w,
                            r2.x,r2.y,r2.z,r2.w, r3.x,r3.y,r3.z,r3.w};
            float y = 0.f;
            #pragma unroll
            for (int n = 0; n < 16; n++) {
                h[n] = __expf(dv * ac[n]) * h[n] + cm * bb[n];
                y += cc[n] * h[n];
            }
            op[(size_t)t * Dr] = y + dp * xr4[u];
        }
    }
}

// ---------------- host ----------------
extern "C" void kernel_launch(void* const* d_in, const int* in_sizes, int n_in,
                              void* d_out, int out_size, void* d_ws, size_t ws_size,
                              hipStream_t stream) {
    const float* x      = (const float*)d_in[0];
    const float* W_dt   = (const float*)d_in[1];
    const float* b_dt   = (const float*)d_in[2];
    const float* W_B    = (const float*)d_in[3];
    const float* W_C    = (const float*)d_in[4];
    const float* Dparam = (const float*)d_in[5];
    const float* A_log  = (const float*)d_in[6];
    const float* gamma  = (const float*)d_in[7];
    const float* beta   = (const float*)d_in[8];
    float* out = (float*)d_out;

    char* ws = (char*)d_ws;
    unsigned short* xnb  = (unsigned short*)(ws);                     // 8 MB
    unsigned short* wcat = (unsigned short*)(ws + 8388608);           // 2.125 MB
    unsigned short* dtb  = (unsigned short*)(ws + 10616832);          // 8 MB (bf16)
    float*          bin  = (float*)(ws + 19005440);                   // 256 KB
    float*          cin  = (float*)(ws + 19267584);                   // 256 KB
    float*          Sws  = (float*)(ws + 19529728);                   // 1 MB (f32, 128 chunks)
    unsigned short* hend = (unsigned short*)(ws + 20578304);          // 8 MB (bf16)
    unsigned short* hin  = (unsigned short*)(ws + 28966912);          // 8 MB  (total ~37 MB)

    ln_pack_kernel<<<M_ROWS + (NPAD * Dr) / 256, 256, 0, stream>>>(
        x, gamma, beta, xnb, W_dt, W_B, W_C, wcat);
    gemm_kernel<<<(M_ROWS / 64) * (NPAD / 64), 64, 0, stream>>>(xnb, wcat, b_dt, dtb, bin, cin);
    dim3 sgrid(Dr / 256, NCH, Bsz);
    scan1_kernel<<<sgrid, 256, 0, stream>>>(dtb, xnb, bin, A_log, Sws, hend);
    combine_kernel<<<(Bsz * Dr * Nr) / 256, 256, 0, stream>>>(Sws, hend, A_log, hin);
    scan2_kernel<<<sgrid, 256, 0, stream>>>(dtb, xnb, bin, cin, A_log, hin, x, Dparam, out);
}